// Round 13
// baseline (135.528 us; speedup 1.0000x reference)
//
#include <hip/hip_runtime.h>
#include <hip/hip_bf16.h>
#include <stdint.h>

#define HWN 50176   // 224*224
#define NM  1000
#define FD  128
#define NSPLIT 49   // 1024-wide k-windows
#define KSTEPS 32
#define NRG 63      // rowgroups of 16 (last clamps)
#define NSCAN 20
#define NPB 50      // 1000 / 20

typedef __attribute__((ext_vector_type(8))) short short8;
typedef __attribute__((ext_vector_type(4))) float f32x4;

__device__ __forceinline__ unsigned short f2bf(float x) {
    union { float f; unsigned u; } v; v.f = x;
    unsigned r = v.u + 0x7FFFu + ((v.u >> 16) & 1u);
    return (unsigned short)(r >> 16);
}

// Stage 1: A[hw,f] = sum_c img*W, packed bf16 k-tiles (GEMM B operand).
// Tile kt (8192B): 16B chunk (f, j) at slot (f*4+j)^((f>>1)&3).
__global__ __launch_bounds__(256) void k_encode(const float* __restrict__ img,
                                                const float* __restrict__ Wt,
                                                unsigned short* __restrict__ Bpack,
                                                float* __restrict__ rep0part)
{
    const int t = threadIdx.x;
    const int f = t & 127;
    const int kt = blockIdx.x * 2 + (t >> 7);
    const int hw0 = kt * 32;
    float vals[32];
    float rsum = 0.f;
#pragma unroll
    for (int e = 0; e < 32; ++e) {
        const int hw = hw0 + e;
        float a = img[hw] * __builtin_nontemporal_load(Wt + (size_t)hw * FD + f);
        a = fmaf(img[HWN + hw],     __builtin_nontemporal_load(Wt + (size_t)(HWN + hw) * FD + f), a);
        a = fmaf(img[2 * HWN + hw], __builtin_nontemporal_load(Wt + (size_t)(2 * HWN + hw) * FD + f), a);
        vals[e] = a;
        rsum += a;
    }
    char* tile = (char*)Bpack + (size_t)kt * 8192;
#pragma unroll
    for (int j = 0; j < 4; ++j) {
        short8 pk;
#pragma unroll
        for (int e = 0; e < 8; ++e) pk[e] = (short)f2bf(vals[j * 8 + e]);
        const int slot = (f * 4 + j) ^ ((f >> 1) & 3);
        *reinterpret_cast<short8*>(tile + (slot << 4)) = pk;
    }
    __shared__ float red[256];
    red[t] = rsum;
    __syncthreads();
    if (t < 128) rep0part[(size_t)blockIdx.x * 128 + f] = red[t] + red[t + 128];
}

// Stage 2: rep0[f] = sum of 784 partials
__global__ __launch_bounds__(256) void k_rep0red(const float* __restrict__ rep0part,
                                                 float* __restrict__ rep0)
{
    const int f = blockIdx.x;
    float s = 0.f;
    for (int b = threadIdx.x; b < 784; b += 256) s += rep0part[(size_t)b * 128 + f];
    __shared__ float red[256];
    red[threadIdx.x] = s;
    __syncthreads();
    for (int o = 128; o > 0; o >>= 1) {
        if (threadIdx.x < o) red[threadIdx.x] += red[threadIdx.x + o];
        __syncthreads();
    }
    if (threadIdx.x == 0) rep0[f] = red[0];
}

// Stage 3: ZERO-LDS ZERO-BARRIER register GEMM. 1 wave = 16 rows x 128 f x
// 1024 k. B fragments load global->VGPR in ONE hop (each bv[ft] wave-op reads
// a 1KB contiguous span of the XCD-L2-resident Bpack split). No LDS, no
// s_barrier, no manual waitcnt: the compiler emits per-load vmcnt and
// software-pipelines across iterations (nothing blocks hoisting).
// Occupancy limited only by VGPR.
__global__ __launch_bounds__(64) void k_gemm(const float* __restrict__ masks,
                                             const unsigned short* __restrict__ Bpack,
                                             float* __restrict__ partial)
{
    const int lane = threadIdx.x & 63;
    const int lrow = lane & 15, kg = lane >> 4;

    // XCD-bijective swizzle: 3087 = 7*386 + 385; xcd<7 gets 386 consecutive.
    const int bid = blockIdx.x;
    const int xcd = bid & 7, idx = bid >> 3;
    const int swz = (xcd < 7 ? xcd * 386 : 2702) + idx;
    const int split = swz / NRG, rg = swz - split * NRG;
    const int n0 = rg * 16;

    int row = n0 + lrow;
    if (row >= NM) row = NM - 1;                   // dup rows never read back
    const float* aSrc = masks + (size_t)row * HWN + split * 1024 + kg * 8;
    const char*  bSrc = (const char*)Bpack + (size_t)split * (KSTEPS * 8192);

    int bo[8];
#pragma unroll
    for (int ft = 0; ft < 8; ++ft) {
        const int f = ft * 16 + lrow;
        bo[ft] = ((f * 4 + kg) ^ ((f >> 1) & 3)) << 4;
    }

    f32x4 acc[8];
#pragma unroll
    for (int i = 0; i < 8; ++i) acc[i] = f32x4{0.f, 0.f, 0.f, 0.f};

#pragma unroll 2
    for (int ks = 0; ks < KSTEPS; ++ks) {
        const char* bt = bSrc + (size_t)ks * 8192;
        short8 bv[8];
#pragma unroll
        for (int ft = 0; ft < 8; ++ft)
            bv[ft] = *reinterpret_cast<const short8*>(bt + bo[ft]);
        const f32x4 a0 = *reinterpret_cast<const f32x4*>(aSrc + ks * 32);
        const f32x4 a1 = *reinterpret_cast<const f32x4*>(aSrc + ks * 32 + 4);

        union { short8 s; __hip_bfloat162 h[4]; } apk;
        apk.h[0] = __float22bfloat162_rn(float2{a0[0], a0[1]});
        apk.h[1] = __float22bfloat162_rn(float2{a0[2], a0[3]});
        apk.h[2] = __float22bfloat162_rn(float2{a1[0], a1[1]});
        apk.h[3] = __float22bfloat162_rn(float2{a1[2], a1[3]});

#pragma unroll
        for (int ft = 0; ft < 8; ++ft)
            acc[ft] = __builtin_amdgcn_mfma_f32_16x16x32_bf16(apk.s, bv[ft], acc[ft], 0, 0, 0);
    }

    // epilogue: C row = n0 + kg*4 + rr, col = ft*16 + lrow
    const int crow = n0 + (kg << 2);
    float* pb = partial + ((size_t)split * 1024 + crow) * FD + lrow;
#pragma unroll
    for (int ft = 0; ft < 8; ++ft)
#pragma unroll
        for (int rr = 0; rr < 4; ++rr)
            __builtin_nontemporal_store(acc[ft][rr], pb + (size_t)rr * FD + ft * 16);
}

// Stage 4: reduce split-K partials (nt loads), cosine sim
__global__ __launch_bounds__(128) void k_sims(const float* __restrict__ partial,
                                              const float* __restrict__ rep0,
                                              float* __restrict__ sims)
{
    const int n = blockIdx.x;
    const int f = threadIdx.x;
    float rsum = 0.f;
    for (int s = 0; s < NSPLIT; ++s)
        rsum += __builtin_nontemporal_load(partial + ((size_t)s * 1024 + n) * FD + f);
    const float r0 = rep0[f];
    __shared__ float red0[128], red1[128], red2[128];
    red0[f] = rsum * r0;
    red1[f] = rsum * rsum;
    red2[f] = r0 * r0;
    __syncthreads();
    for (int o = 64; o > 0; o >>= 1) {
        if (f < o) {
            red0[f] += red0[f + o];
            red1[f] += red1[f + o];
            red2[f] += red2[f + o];
        }
        __syncthreads();
    }
    if (f == 0) {
        const float nr = fmaxf(sqrtf(red1[0]), 1e-8f);
        const float nz = fmaxf(sqrtf(red2[0]), 1e-8f);
        sims[n] = red0[0] / (nr * nz);
    }
}

// Stage 5a: per-pixel weighted sums S0,S1,S2 over an n-chunk, float4 pixels
__global__ __launch_bounds__(256) void k_colsums(const float* __restrict__ masks,
                                                 const float* __restrict__ sims,
                                                 float* __restrict__ Spart)
{
    __shared__ float s1v[NPB], s2v[NPB];
    const int t = threadIdx.x;
    const int split = blockIdx.y;
    if (t < NPB) {
        const float s = sims[split * NPB + t];
        s1v[t] = s;
        s2v[t] = s * s;
    }
    __syncthreads();
    const int pix = (blockIdx.x * 256 + t) * 4;
    const float* mp = masks + (size_t)split * NPB * HWN + pix;
    f32x4 s0 = {0.f,0.f,0.f,0.f}, s1 = s0, s2 = s0;
#pragma unroll 5
    for (int i = 0; i < NPB; ++i) {
        const f32x4 m = *reinterpret_cast<const f32x4*>(mp + (size_t)i * HWN);
        const float a = s1v[i], b = s2v[i];
        s0 += m;
#pragma unroll
        for (int e = 0; e < 4; ++e) {
            s1[e] = fmaf(m[e], a, s1[e]);
            s2[e] = fmaf(m[e], b, s2[e]);
        }
    }
    float* sp = Spart + (size_t)split * 3 * HWN + pix;
    __builtin_nontemporal_store(s0, reinterpret_cast<f32x4*>(sp));
    __builtin_nontemporal_store(s1, reinterpret_cast<f32x4*>(sp + HWN));
    __builtin_nontemporal_store(s2, reinterpret_cast<f32x4*>(sp + 2 * HWN));
}

// Stage 5b: combine splits, closed-form imp/unc/sow
__global__ __launch_bounds__(256) void k_final(const float* __restrict__ Spart,
                                               float* __restrict__ out)
{
    const int pix = (blockIdx.x * 256 + threadIdx.x) * 4;
    f32x4 s0 = {0.f,0.f,0.f,0.f}, s1 = s0, s2 = s0;
#pragma unroll 4
    for (int sp = 0; sp < NSCAN; ++sp) {
        const float* p = Spart + (size_t)sp * 3 * HWN + pix;
        s0 += __builtin_nontemporal_load(reinterpret_cast<const f32x4*>(p));
        s1 += __builtin_nontemporal_load(reinterpret_cast<const f32x4*>(p + HWN));
        s2 += __builtin_nontemporal_load(reinterpret_cast<const f32x4*>(p + 2 * HWN));
    }
    f32x4 imp, unc, sow;
#pragma unroll
    for (int e = 0; e < 4; ++e) {
        sow[e] = 1e-10f + s0[e];
        imp[e] = s1[e] / sow[e];
        unc[e] = fmaf(-imp[e], s1[e], s2[e]);   // S2 - S1^2/sow
    }
    *reinterpret_cast<f32x4*>(out + pix) = imp;
    *reinterpret_cast<f32x4*>(out + HWN + pix) = unc;
    *reinterpret_cast<f32x4*>(out + 2 * HWN + pix) = sow;
}

extern "C" void kernel_launch(void* const* d_in, const int* in_sizes, int n_in,
                              void* d_out, int out_size, void* d_ws, size_t ws_size,
                              hipStream_t stream) {
    const float* img   = (const float*)d_in[0];
    const float* masks = (const float*)d_in[1];
    const float* Wt    = (const float*)d_in[2];
    float* out = (float*)d_out;

    char* ws = (char*)d_ws;
    unsigned short* Bpack = (unsigned short*)ws;                 // 12,845,056 B
    float* partial  = (float*)(ws + 12845056);                   // 25,690,112 B
    float* rep0part = partial;                                   // alias: consumed before gemm writes
    float* rep0     = (float*)(ws + 38535168);                   // 512 B
    float* sims     = (float*)(ws + 38535680);                   // 4,000 B
    float* Spart    = (float*)ws;                                // alias Bpack (12,042,240 B)

    hipLaunchKernelGGL(k_encode,  dim3(784), dim3(256), 0, stream, img, Wt, Bpack, rep0part);
    hipLaunchKernelGGL(k_rep0red, dim3(128), dim3(256), 0, stream, rep0part, rep0);
    hipLaunchKernelGGL(k_gemm,    dim3(3087), dim3(64), 0, stream, masks, Bpack, partial);
    hipLaunchKernelGGL(k_sims,    dim3(NM), dim3(128), 0, stream, partial, rep0, sims);
    hipLaunchKernelGGL(k_colsums, dim3(49, NSCAN), dim3(256), 0, stream, masks, sims, Spart);
    hipLaunchKernelGGL(k_final,   dim3(49), dim3(256), 0, stream, Spart, out);
}

// Round 14
// 123.079 us; speedup vs baseline: 1.1011x; 1.1011x over previous
//
#include <hip/hip_runtime.h>
#include <hip/hip_bf16.h>
#include <stdint.h>

#define HWN 50176   // 224*224
#define NM  1000
#define FD  128
#define NSPLIT 49   // 1024-wide k-chunks
#define KSTEPS 32
#define NSCAN 20
#define NPB 50      // 1000 / 20

typedef __attribute__((ext_vector_type(8))) short short8;
typedef __attribute__((ext_vector_type(4))) float f32x4;

__device__ __forceinline__ unsigned short f2bf(float x) {
    union { float f; unsigned u; } v; v.f = x;
    unsigned r = v.u + 0x7FFFu + ((v.u >> 16) & 1u);
    return (unsigned short)(r >> 16);
}

#define AS1(p) ((const __attribute__((address_space(1))) unsigned int*)(p))
#define AS3(p) ((__attribute__((address_space(3))) unsigned int*)(p))

// Stage 1: A[hw,f] = sum_c img*W, packed bf16 k-tiles (GEMM B operand).
// Tile kt (8192B): 16B chunk (f, j) at slot (f*4+j)^((f>>1)&3).
// W read nontemporal: streamed once, keep masks L3-resident.
__global__ __launch_bounds__(256) void k_encode(const float* __restrict__ img,
                                                const float* __restrict__ Wt,
                                                unsigned short* __restrict__ Bpack,
                                                float* __restrict__ rep0part)
{
    const int t = threadIdx.x;
    const int f = t & 127;
    const int kt = blockIdx.x * 2 + (t >> 7);
    const int hw0 = kt * 32;
    float vals[32];
    float rsum = 0.f;
#pragma unroll
    for (int e = 0; e < 32; ++e) {
        const int hw = hw0 + e;
        float a = img[hw] * __builtin_nontemporal_load(Wt + (size_t)hw * FD + f);
        a = fmaf(img[HWN + hw],     __builtin_nontemporal_load(Wt + (size_t)(HWN + hw) * FD + f), a);
        a = fmaf(img[2 * HWN + hw], __builtin_nontemporal_load(Wt + (size_t)(2 * HWN + hw) * FD + f), a);
        vals[e] = a;
        rsum += a;
    }
    char* tile = (char*)Bpack + (size_t)kt * 8192;
#pragma unroll
    for (int j = 0; j < 4; ++j) {
        short8 pk;
#pragma unroll
        for (int e = 0; e < 8; ++e) pk[e] = (short)f2bf(vals[j * 8 + e]);
        const int slot = (f * 4 + j) ^ ((f >> 1) & 3);
        *reinterpret_cast<short8*>(tile + (slot << 4)) = pk;
    }
    __shared__ float red[256];
    red[t] = rsum;
    __syncthreads();
    if (t < 128) rep0part[(size_t)blockIdx.x * 128 + f] = red[t] + red[t + 128];
}

// Stage 2: rep0[f] = sum of 784 partials
__global__ __launch_bounds__(256) void k_rep0red(const float* __restrict__ rep0part,
                                                 float* __restrict__ rep0)
{
    const int f = blockIdx.x;
    float s = 0.f;
    for (int b = threadIdx.x; b < 784; b += 256) s += rep0part[(size_t)b * 128 + f];
    __shared__ float red[256];
    red[threadIdx.x] = s;
    __syncthreads();
    for (int o = 128; o > 0; o >>= 1) {
        if (threadIdx.x < o) red[threadIdx.x] += red[threadIdx.x + o];
        __syncthreads();
    }
    if (threadIdx.x == 0) rep0[f] = red[0];
}

// Stage 3: split-K GEMM. 64-row tile, 4 waves/256 thr, grid 16x49=784.
// A (masks) in REGISTERS, depth-2 prefetch. B via global_load_lds, 3 buffers.
// Exact counted vmcnt: 4 vmem ops/step (2 B-gll + 2 A-loads) inside fences;
// steady-state wait vmcnt(8); never drains inside the loop.
__global__ __launch_bounds__(256, 4) void k_gemm(const float* __restrict__ masks,
                                                 const unsigned short* __restrict__ Bpack,
                                                 float* __restrict__ partial)
{
    __shared__ __align__(16) char Bs[3][8192];

    const int t = threadIdx.x;
    const int wv = t >> 6, lane = t & 63;
    const int lrow = lane & 15, kg = lane >> 4;

    // XCD-bijective swizzle (784 = 8*98): XCD x gets contiguous swz range.
    const int bid = blockIdx.x;
    const int swz = (bid & 7) * 98 + (bid >> 3);
    const int split = swz >> 4, mtile = swz & 15;
    const int n0 = mtile * 64;

    int row = n0 + wv * 16 + lrow;
    if (row >= NM) row = NM - 1;                  // dup rows never read back
    const float* aSrc = masks + (size_t)row * HWN + split * 1024 + kg * 8;
    const char*  bSrc = (const char*)Bpack + (size_t)split * (KSTEPS * 8192) + t * 16;

    int bo[8];
#pragma unroll
    for (int ft = 0; ft < 8; ++ft) {
        const int f = ft * 16 + lrow;
        bo[ft] = ((f * 4 + kg) ^ ((f >> 1) & 3)) << 4;
    }

    f32x4 acc[8];
#pragma unroll
    for (int i = 0; i < 8; ++i) acc[i] = f32x4{0.f, 0.f, 0.f, 0.f};

    // Named rotating A-register buffers (static indexing only — rule #20).
    f32x4 aA0, aA1, aB0, aB1, aC0, aC1;

#define STAGE(KS, BUFOFF) do {                                                                     \
        __builtin_amdgcn_global_load_lds(AS1(bSrc + (size_t)(KS) * 8192),        AS3(&Bs[0][0] + (BUFOFF) + ((t & 255) * 16)), 16, 0, 0); \
        __builtin_amdgcn_global_load_lds(AS1(bSrc + (size_t)(KS) * 8192 + 4096), AS3(&Bs[0][0] + (BUFOFF) + 4096 + ((t & 255) * 16)), 16, 0, 0); \
    } while (0)
    // NOTE: both gll lines stage 4KB each (256 thr x 16B); second covers +4096.

    // prologue: steps 0,1 in flight (8 vmem ops)
    __builtin_amdgcn_sched_barrier(0);
    STAGE(0, 0);
    aA0 = *reinterpret_cast<const f32x4*>(aSrc);
    aA1 = *reinterpret_cast<const f32x4*>(aSrc + 4);
    __builtin_amdgcn_sched_barrier(0);
    STAGE(1, 8192);
    aB0 = *reinterpret_cast<const f32x4*>(aSrc + 32);
    aB1 = *reinterpret_cast<const f32x4*>(aSrc + 36);
    __builtin_amdgcn_sched_barrier(0);

    int boff_c = 0;          // buffer offset of step ks
    for (int ks = 0; ks < KSTEPS; ++ks) {
        const int boff_s = (boff_c + 16384 >= 24576) ? (boff_c + 16384 - 24576) : (boff_c + 16384);
        if (ks + 2 < KSTEPS) {
            __builtin_amdgcn_sched_barrier(0);
            STAGE(ks + 2, boff_s);
            aC0 = *reinterpret_cast<const f32x4*>(aSrc + (ks + 2) * 32);
            aC1 = *reinterpret_cast<const f32x4*>(aSrc + (ks + 2) * 32 + 4);
            __builtin_amdgcn_sched_barrier(0);
            asm volatile("s_waitcnt vmcnt(8)" ::: "memory");   // step ks fully landed
        } else if (ks == KSTEPS - 2) {
            asm volatile("s_waitcnt vmcnt(4)" ::: "memory");
        } else {
            asm volatile("s_waitcnt vmcnt(0)" ::: "memory");
        }
        __builtin_amdgcn_s_barrier();            // buf[ks] visible to all waves
        __builtin_amdgcn_sched_barrier(0);

        const char* B = &Bs[0][0] + boff_c;
        short8 bfv[8];
#pragma unroll
        for (int ft = 0; ft < 8; ++ft)
            bfv[ft] = *reinterpret_cast<const short8*>(B + bo[ft]);

        union { short8 s; __hip_bfloat162 h[4]; } apk;
        apk.h[0] = __float22bfloat162_rn(float2{aA0[0], aA0[1]});
        apk.h[1] = __float22bfloat162_rn(float2{aA0[2], aA0[3]});
        apk.h[2] = __float22bfloat162_rn(float2{aA1[0], aA1[1]});
        apk.h[3] = __float22bfloat162_rn(float2{aA1[2], aA1[3]});

        asm volatile("s_waitcnt lgkmcnt(0)" ::: "memory");
        __builtin_amdgcn_sched_barrier(0);
        __builtin_amdgcn_s_setprio(1);
#pragma unroll
        for (int ft = 0; ft < 8; ++ft)
            acc[ft] = __builtin_amdgcn_mfma_f32_16x16x32_bf16(apk.s, bfv[ft], acc[ft], 0, 0, 0);
        __builtin_amdgcn_s_setprio(0);
        __builtin_amdgcn_sched_barrier(0);
        if (ks + 1 < KSTEPS) {
            __builtin_amdgcn_s_barrier();        // frag reads done before staging over buf
            __builtin_amdgcn_sched_barrier(0);
        }
        // rotate A-regs and buffer offset
        aA0 = aB0; aA1 = aB1; aB0 = aC0; aB1 = aC1;
        boff_c = (boff_c + 8192 >= 24576) ? 0 : (boff_c + 8192);
    }
#undef STAGE

    // epilogue: C row = n0 + wv*16 + kg*4 + rr, col = ft*16 + lrow
    const int crow = n0 + wv * 16 + (kg << 2);
    float* pb = partial + ((size_t)split * 1024 + crow) * FD + lrow;
#pragma unroll
    for (int ft = 0; ft < 8; ++ft)
#pragma unroll
        for (int rr = 0; rr < 4; ++rr)
            __builtin_nontemporal_store(acc[ft][rr], pb + (size_t)rr * FD + ft * 16);
}

// Stage 4: reduce split-K partials (nt loads), cosine sim
__global__ __launch_bounds__(128) void k_sims(const float* __restrict__ partial,
                                              const float* __restrict__ rep0,
                                              float* __restrict__ sims)
{
    const int n = blockIdx.x;
    const int f = threadIdx.x;
    float rsum = 0.f;
    for (int s = 0; s < NSPLIT; ++s)
        rsum += __builtin_nontemporal_load(partial + ((size_t)s * 1024 + n) * FD + f);
    const float r0 = rep0[f];
    __shared__ float red0[128], red1[128], red2[128];
    red0[f] = rsum * r0;
    red1[f] = rsum * rsum;
    red2[f] = r0 * r0;
    __syncthreads();
    for (int o = 64; o > 0; o >>= 1) {
        if (f < o) {
            red0[f] += red0[f + o];
            red1[f] += red1[f + o];
            red2[f] += red2[f + o];
        }
        __syncthreads();
    }
    if (f == 0) {
        const float nr = fmaxf(sqrtf(red1[0]), 1e-8f);
        const float nz = fmaxf(sqrtf(red2[0]), 1e-8f);
        sims[n] = red0[0] / (nr * nz);
    }
}

// Stage 5a: per-pixel weighted sums S0,S1,S2 over an n-chunk, float4 pixels
__global__ __launch_bounds__(256) void k_colsums(const float* __restrict__ masks,
                                                 const float* __restrict__ sims,
                                                 float* __restrict__ Spart)
{
    __shared__ float s1v[NPB], s2v[NPB];
    const int t = threadIdx.x;
    const int split = blockIdx.y;
    if (t < NPB) {
        const float s = sims[split * NPB + t];
        s1v[t] = s;
        s2v[t] = s * s;
    }
    __syncthreads();
    const int pix = (blockIdx.x * 256 + t) * 4;
    const float* mp = masks + (size_t)split * NPB * HWN + pix;
    f32x4 s0 = {0.f,0.f,0.f,0.f}, s1 = s0, s2 = s0;
#pragma unroll 5
    for (int i = 0; i < NPB; ++i) {
        const f32x4 m = *reinterpret_cast<const f32x4*>(mp + (size_t)i * HWN);
        const float a = s1v[i], b = s2v[i];
        s0 += m;
#pragma unroll
        for (int e = 0; e < 4; ++e) {
            s1[e] = fmaf(m[e], a, s1[e]);
            s2[e] = fmaf(m[e], b, s2[e]);
        }
    }
    float* sp = Spart + (size_t)split * 3 * HWN + pix;
    __builtin_nontemporal_store(s0, reinterpret_cast<f32x4*>(sp));
    __builtin_nontemporal_store(s1, reinterpret_cast<f32x4*>(sp + HWN));
    __builtin_nontemporal_store(s2, reinterpret_cast<f32x4*>(sp + 2 * HWN));
}

// Stage 5b: combine splits, closed-form imp/unc/sow
__global__ __launch_bounds__(256) void k_final(const float* __restrict__ Spart,
                                               float* __restrict__ out)
{
    const int pix = (blockIdx.x * 256 + threadIdx.x) * 4;
    f32x4 s0 = {0.f,0.f,0.f,0.f}, s1 = s0, s2 = s0;
#pragma unroll 4
    for (int sp = 0; sp < NSCAN; ++sp) {
        const float* p = Spart + (size_t)sp * 3 * HWN + pix;
        s0 += __builtin_nontemporal_load(reinterpret_cast<const f32x4*>(p));
        s1 += __builtin_nontemporal_load(reinterpret_cast<const f32x4*>(p + HWN));
        s2 += __builtin_nontemporal_load(reinterpret_cast<const f32x4*>(p + 2 * HWN));
    }
    f32x4 imp, unc, sow;
#pragma unroll
    for (int e = 0; e < 4; ++e) {
        sow[e] = 1e-10f + s0[e];
        imp[e] = s1[e] / sow[e];
        unc[e] = fmaf(-imp[e], s1[e], s2[e]);   // S2 - S1^2/sow
    }
    *reinterpret_cast<f32x4*>(out + pix) = imp;
    *reinterpret_cast<f32x4*>(out + HWN + pix) = unc;
    *reinterpret_cast<f32x4*>(out + 2 * HWN + pix) = sow;
}

extern "C" void kernel_launch(void* const* d_in, const int* in_sizes, int n_in,
                              void* d_out, int out_size, void* d_ws, size_t ws_size,
                              hipStream_t stream) {
    const float* img   = (const float*)d_in[0];
    const float* masks = (const float*)d_in[1];
    const float* Wt    = (const float*)d_in[2];
    float* out = (float*)d_out;

    char* ws = (char*)d_ws;
    unsigned short* Bpack = (unsigned short*)ws;                 // 12,845,056 B
    float* partial  = (float*)(ws + 12845056);                   // 49*1024*128*4 = 25,690,112 B
    float* rep0part = partial;                                   // alias: consumed before gemm writes
    float* rep0     = (float*)(ws + 38535168);                   // 512 B
    float* sims     = (float*)(ws + 38535680);                   // 4,000 B
    float* Spart    = (float*)ws;                                // alias Bpack (12,042,240 B)

    hipLaunchKernelGGL(k_encode,  dim3(784), dim3(256), 0, stream, img, Wt, Bpack, rep0part);
    hipLaunchKernelGGL(k_rep0red, dim3(128), dim3(256), 0, stream, rep0part, rep0);
    hipLaunchKernelGGL(k_gemm,    dim3(784), dim3(256), 0, stream, masks, Bpack, partial);
    hipLaunchKernelGGL(k_sims,    dim3(NM), dim3(128), 0, stream, partial, rep0, sims);
    hipLaunchKernelGGL(k_colsums, dim3(49, NSCAN), dim3(256), 0, stream, masks, sims, Spart);
    hipLaunchKernelGGL(k_final,   dim3(49), dim3(256), 0, stream, Spart, out);
}